// Round 2
// baseline (576.526 us; speedup 1.0000x reference)
//
#include <hip/hip_runtime.h>

#define BB 16
#define SS 512
#define KIN 512
#define H 256

constexpr float DECAY = 0.951229424500714f;    // exp(-1/20), both tau=20
constexpr float OMD   = 0.048770575499286f;    // 1 - exp(-1/20)
constexpr float LR    = 0.01f;
constexpr float WMAX  = 1.0f;

__device__ __forceinline__ float fast_tanh(float x) {
    float e = __expf(2.f * x);
    return 1.f - __fdividef(2.f, e + 1.f);
}

// Full 64-lane sum via DPP (VALU pipe, no LDS), result broadcast via SGPR.
// Canonical gfx9 sequence: prefix-sum within 16-lane rows (row_shr 1,2,4,8),
// then row_bcast15 (rows 1,3) and row_bcast31 (rows 2,3); lane 63 = total.
__device__ __forceinline__ float wave_sum64(float x) {
    int t;
    t = __builtin_amdgcn_update_dpp(0, __float_as_int(x), 0x111, 0xf, 0xf, false);
    x += __int_as_float(t);
    t = __builtin_amdgcn_update_dpp(0, __float_as_int(x), 0x112, 0xf, 0xf, false);
    x += __int_as_float(t);
    t = __builtin_amdgcn_update_dpp(0, __float_as_int(x), 0x114, 0xf, 0xf, false);
    x += __int_as_float(t);
    t = __builtin_amdgcn_update_dpp(0, __float_as_int(x), 0x118, 0xf, 0xf, false);
    x += __int_as_float(t);
    t = __builtin_amdgcn_update_dpp(0, __float_as_int(x), 0x142, 0xa, 0xf, false);
    x += __int_as_float(t);
    t = __builtin_amdgcn_update_dpp(0, __float_as_int(x), 0x143, 0xc, 0xf, false);
    x += __int_as_float(t);
    return __int_as_float(__builtin_amdgcn_readlane(__float_as_int(x), 63));
}

// OUT[m][n] = sum_k X[m][k] * W[n][k];  X:[8192,512], W:[512,512], OUT:[8192,512]
__global__ __launch_bounds__(256) void gemm_xwT(const float* __restrict__ X,
                                                const float* __restrict__ W,
                                                float* __restrict__ OUT) {
    __shared__ float As[16][68];
    __shared__ float Bs[16][68];
    const int m0 = blockIdx.y * 64;
    const int n0 = blockIdx.x * 64;
    const int tid = threadIdx.x;
    const int r  = tid >> 2;   // 0..63
    const int cg = tid & 3;    // 0..3
    const int tx = tid & 15;   // n sub
    const int ty = tid >> 4;   // m sub
    float acc[4][4] = {};
    for (int k0 = 0; k0 < KIN; k0 += 16) {
        float4 av = *(const float4*)&X[(size_t)(m0 + r) * KIN + k0 + cg * 4];
        float4 bv = *(const float4*)&W[(size_t)(n0 + r) * KIN + k0 + cg * 4];
        __syncthreads();
        As[cg*4+0][r] = av.x; As[cg*4+1][r] = av.y; As[cg*4+2][r] = av.z; As[cg*4+3][r] = av.w;
        Bs[cg*4+0][r] = bv.x; Bs[cg*4+1][r] = bv.y; Bs[cg*4+2][r] = bv.z; Bs[cg*4+3][r] = bv.w;
        __syncthreads();
#pragma unroll
        for (int kk = 0; kk < 16; ++kk) {
            float4 a = *(const float4*)&As[kk][ty * 4];
            float4 b = *(const float4*)&Bs[kk][tx * 4];
            float ar[4] = {a.x, a.y, a.z, a.w};
            float br[4] = {b.x, b.y, b.z, b.w};
#pragma unroll
            for (int i = 0; i < 4; ++i)
#pragma unroll
                for (int j = 0; j < 4; ++j) acc[i][j] += ar[i] * br[j];
        }
    }
#pragma unroll
    for (int i = 0; i < 4; ++i) {
        float4 o = make_float4(acc[i][0], acc[i][1], acc[i][2], acc[i][3]);
        *(float4*)&OUT[(size_t)(m0 + ty * 4 + i) * KIN + n0 + tx * 4] = o;
    }
}

// cur: [B, S, 512] (ik = [:,:,0:256], iv = [:,:,256:512])
// One wave per mem-row. Each lane owns 4 mem columns AND the kv state for
// those same 4 columns -> no LDS, no barrier. 4 independent waves per block.
__global__ __launch_bounds__(256) void scan_kernel(const float* __restrict__ cur,
                                                   float* __restrict__ mem_out,
                                                   float* __restrict__ keys,
                                                   float* __restrict__ vals) {
    const int b    = blockIdx.x >> 6;
    const int rg   = blockIdx.x & 63;
    const int tid  = threadIdx.x;
    const int wave = tid >> 6;
    const int lane = tid & 63;
    const int row  = rg * 4 + wave;

    const float* curb = cur + (size_t)b * SS * 512;
    float* keyout = keys + (size_t)b * SS * H;
    float* valout = vals + (size_t)b * SS * H;

    float mem[4] = {0.f, 0.f, 0.f, 0.f};
    float ktr[4] = {0.f, 0.f, 0.f, 0.f};
    float kvv[4] = {0.f, 0.f, 0.f, 0.f};
    float vv = 0.f, vt = 0.f;

    const bool store_keys = (rg == 0) && (wave == 0);

    // prefetch t=0 currents
    float4 ik  = *(const float4*)&curb[lane * 4];
    float  ivt = curb[256 + row];

    for (int t = 0; t < SS; ++t) {
        // prefetch next step's currents (in flight across the step)
        const int tn = (t + 1 < SS) ? (t + 1) : t;
        const float* curn = curb + (size_t)tn * 512;
        float4 ikn = *(const float4*)&curn[lane * 4];
        float  ivn = curn[256 + row];

        // key dynamics for this lane's own 4 columns
        float ikr[4] = {ik.x, ik.y, ik.z, ik.w};
        float keyv[4];
#pragma unroll
        for (int q = 0; q < 4; ++q) {
            kvv[q] = DECAY * kvv[q] + ikr[q];
            keyv[q] = fast_tanh(kvv[q]);
        }

        // memory readout: row dot key, summed across the wave on the VALU pipe
        float p = mem[0] * keyv[0] + mem[1] * keyv[1] + mem[2] * keyv[2] + mem[3] * keyv[3];
        float ikv = 0.2f * wave_sum64(p);

        // value dynamics (uniform across the wave)
        vv = DECAY * vv + ivt + ikv;
        float valv = fast_tanh(vv);
        vt = DECAY * vt + OMD * valv;

        if (store_keys)
            *(float4*)&keyout[t * H + lane * 4] = make_float4(keyv[0], keyv[1], keyv[2], keyv[3]);
        if (lane == 0)
            valout[t * H + row] = valv;

        // traces + soft-bounded Hebbian update for this lane's 4 columns
        float c = LR * vt;
#pragma unroll
        for (int q = 0; q < 4; ++q) {
            ktr[q] = DECAY * ktr[q] + OMD * keyv[q];
            mem[q] += c * ktr[q] * (WMAX - mem[q]);
        }

        ik = ikn;
        ivt = ivn;
    }

    *(float4*)&mem_out[((size_t)b * H + row) * H + lane * 4] =
        make_float4(mem[0], mem[1], mem[2], mem[3]);
}

extern "C" void kernel_launch(void* const* d_in, const int* in_sizes, int n_in,
                              void* d_out, int out_size, void* d_ws, size_t ws_size,
                              hipStream_t stream) {
    const float* x = (const float*)d_in[0];   // [B, S, IN] f32
    const float* W = (const float*)d_in[1];   // [2H, IN] f32
    float* out = (float*)d_out;
    float* mem_out = out;                               // [B, H, H]
    float* keys = out + (size_t)BB * H * H;             // [B, S, H]
    float* vals = keys + (size_t)BB * SS * H;           // [B, S, H]
    float* cur = (float*)d_ws;                          // [B, S, 512] = 16 MB

    dim3 gb(8, 128);  // N/64, M/64  (M = B*S = 8192, N = 2H = 512)
    gemm_xwT<<<gb, 256, 0, stream>>>(x, W, cur);
    scan_kernel<<<1024, 256, 0, stream>>>(cur, mem_out, keys, vals);
}

// Round 3
// 385.030 us; speedup vs baseline: 1.4974x; 1.4974x over previous
//
#include <hip/hip_runtime.h>

#define BB 16
#define SS 512
#define KIN 512
#define H 256

constexpr float DECAY = 0.951229424500714f;    // exp(-1/20), both tau=20
constexpr float OMD   = 0.048770575499286f;    // 1 - exp(-1/20)
constexpr float LR    = 0.01f;
constexpr float WMAX  = 1.0f;

__device__ __forceinline__ float fast_tanh(float x) {
    float e = __expf(2.f * x);
    return 1.f - __fdividef(2.f, e + 1.f);
}

// Sum within each 32-lane half; returns sums via readlane(31) / readlane(63).
// 4x row_shr prefix within 16-rows, then row_bcast15 adds lane15->lanes16-31
// (row_mask 0xa) so lane31 = sum(0..31), lane63 = sum(32..63).
__device__ __forceinline__ void half_sum32(float x, float& s_lo, float& s_hi) {
    int t;
    t = __builtin_amdgcn_update_dpp(0, __float_as_int(x), 0x111, 0xf, 0xf, false);
    x += __int_as_float(t);
    t = __builtin_amdgcn_update_dpp(0, __float_as_int(x), 0x112, 0xf, 0xf, false);
    x += __int_as_float(t);
    t = __builtin_amdgcn_update_dpp(0, __float_as_int(x), 0x114, 0xf, 0xf, false);
    x += __int_as_float(t);
    t = __builtin_amdgcn_update_dpp(0, __float_as_int(x), 0x118, 0xf, 0xf, false);
    x += __int_as_float(t);
    t = __builtin_amdgcn_update_dpp(0, __float_as_int(x), 0x142, 0xa, 0xf, false);
    x += __int_as_float(t);
    s_lo = __int_as_float(__builtin_amdgcn_readlane(__float_as_int(x), 31));
    s_hi = __int_as_float(__builtin_amdgcn_readlane(__float_as_int(x), 63));
}

// OUT[m][n] = sum_k X[m][k] * W[n][k];  X:[8192,512], W:[512,512], OUT:[8192,512]
__global__ __launch_bounds__(256) void gemm_xwT(const float* __restrict__ X,
                                                const float* __restrict__ W,
                                                float* __restrict__ OUT) {
    __shared__ float As[16][68];
    __shared__ float Bs[16][68];
    const int m0 = blockIdx.y * 64;
    const int n0 = blockIdx.x * 64;
    const int tid = threadIdx.x;
    const int r  = tid >> 2;
    const int cg = tid & 3;
    const int tx = tid & 15;
    const int ty = tid >> 4;
    float acc[4][4] = {};
    for (int k0 = 0; k0 < KIN; k0 += 16) {
        float4 av = *(const float4*)&X[(size_t)(m0 + r) * KIN + k0 + cg * 4];
        float4 bv = *(const float4*)&W[(size_t)(n0 + r) * KIN + k0 + cg * 4];
        __syncthreads();
        As[cg*4+0][r] = av.x; As[cg*4+1][r] = av.y; As[cg*4+2][r] = av.z; As[cg*4+3][r] = av.w;
        Bs[cg*4+0][r] = bv.x; Bs[cg*4+1][r] = bv.y; Bs[cg*4+2][r] = bv.z; Bs[cg*4+3][r] = bv.w;
        __syncthreads();
#pragma unroll
        for (int kk = 0; kk < 16; ++kk) {
            float4 a = *(const float4*)&As[kk][ty * 4];
            float4 b = *(const float4*)&Bs[kk][tx * 4];
            float ar[4] = {a.x, a.y, a.z, a.w};
            float br[4] = {b.x, b.y, b.z, b.w};
#pragma unroll
            for (int i = 0; i < 4; ++i)
#pragma unroll
                for (int j = 0; j < 4; ++j) acc[i][j] += ar[i] * br[j];
        }
    }
#pragma unroll
    for (int i = 0; i < 4; ++i) {
        float4 o = make_float4(acc[i][0], acc[i][1], acc[i][2], acc[i][3]);
        *(float4*)&OUT[(size_t)(m0 + ty * 4 + i) * KIN + n0 + tx * 4] = o;
    }
}

// Per (b, col): scan kv/key/kt over time. Writes key to output; overwrites the
// ik slot in cur with kt (consumed by value_scan; regenerated by gemm each call).
__global__ __launch_bounds__(64) void key_scan(float* __restrict__ cur,
                                               float* __restrict__ keys) {
    const int idx = blockIdx.x * 64 + threadIdx.x;   // 0..4095
    const int b   = idx >> 8;
    const int col = idx & 255;
    float* c  = cur  + (size_t)b * SS * 512 + col;
    float* ko = keys + (size_t)b * SS * H + col;
    float kv = 0.f, kt = 0.f;
    float ik = c[0];
    for (int t = 0; t < SS; ++t) {
        float ikn = (t + 1 < SS) ? c[(size_t)(t + 1) * 512] : 0.f;
        kv = DECAY * kv + ik;
        float key = fast_tanh(kv);
        kt = DECAY * kt + OMD * key;
        ko[(size_t)t * H] = key;
        c[(size_t)t * 512] = kt;
        ik = ikn;
    }
}

// cur: [B,S,512] with cols 0-255 = kt (from key_scan), 256-511 = iv.
// 2 mem-rows per wave: 32 lanes per row, 8 columns per lane. 4 waves/block.
__global__ __launch_bounds__(256) void value_scan(const float* __restrict__ cur,
                                                  const float* __restrict__ keys,
                                                  float* __restrict__ mem_out,
                                                  float* __restrict__ vals) {
    const int tid  = threadIdx.x;
    const int wave = tid >> 6;
    const int lane = tid & 63;
    const int half = lane >> 5;
    const int sub  = lane & 31;
    const int b    = blockIdx.x >> 5;    // 32 blocks per batch
    const int rg   = blockIdx.x & 31;
    const int row  = rg * 8 + wave * 2 + half;

    const float* ktp  = cur  + (size_t)b * SS * 512 + sub * 8;
    const float* ivp  = cur  + (size_t)b * SS * 512 + 256 + row;
    const float* keyp = keys + (size_t)b * SS * H + sub * 8;
    float* valout = vals + (size_t)b * SS * H;

    float mem[8] = {0.f, 0.f, 0.f, 0.f, 0.f, 0.f, 0.f, 0.f};
    float vv = 0.f, vt = 0.f;

    // prefetch t=0
    float4 ck0  = *(const float4*)&keyp[0];
    float4 ck1  = *(const float4*)&keyp[4];
    float4 ckt0 = *(const float4*)&ktp[0];
    float4 ckt1 = *(const float4*)&ktp[4];
    float  civ  = ivp[0];

    for (int t = 0; t < SS; ++t) {
        const int tn = (t + 1 < SS) ? (t + 1) : t;
        float4 nk0  = *(const float4*)&keyp[(size_t)tn * H];
        float4 nk1  = *(const float4*)&keyp[(size_t)tn * H + 4];
        float4 nkt0 = *(const float4*)&ktp[(size_t)tn * 512];
        float4 nkt1 = *(const float4*)&ktp[(size_t)tn * 512 + 4];
        float  niv  = ivp[(size_t)tn * 512];

        // readout: this row dotted with key, reduced over the 32-lane half
        float p = mem[0] * ck0.x + mem[1] * ck0.y + mem[2] * ck0.z + mem[3] * ck0.w
                + mem[4] * ck1.x + mem[5] * ck1.y + mem[6] * ck1.z + mem[7] * ck1.w;
        float s_lo, s_hi;
        half_sum32(p, s_lo, s_hi);
        float ikv = 0.2f * (half ? s_hi : s_lo);

        // value dynamics (redundant across the 32 lanes of this row)
        vv = DECAY * vv + civ + ikv;
        float valv = fast_tanh(vv);
        vt = DECAY * vt + OMD * valv;
        if (sub == 0) valout[(size_t)t * H + row] = valv;

        // soft-bounded Hebbian update, kt precomputed
        float c = LR * vt;
        float ktr[8] = {ckt0.x, ckt0.y, ckt0.z, ckt0.w, ckt1.x, ckt1.y, ckt1.z, ckt1.w};
#pragma unroll
        for (int q = 0; q < 8; ++q)
            mem[q] += (c * ktr[q]) * (WMAX - mem[q]);

        ck0 = nk0; ck1 = nk1; ckt0 = nkt0; ckt1 = nkt1; civ = niv;
    }

    float* mo = &mem_out[((size_t)b * H + row) * H + sub * 8];
    *(float4*)&mo[0] = make_float4(mem[0], mem[1], mem[2], mem[3]);
    *(float4*)&mo[4] = make_float4(mem[4], mem[5], mem[6], mem[7]);
}

extern "C" void kernel_launch(void* const* d_in, const int* in_sizes, int n_in,
                              void* d_out, int out_size, void* d_ws, size_t ws_size,
                              hipStream_t stream) {
    const float* x = (const float*)d_in[0];   // [B, S, IN] f32
    const float* W = (const float*)d_in[1];   // [2H, IN] f32
    float* out = (float*)d_out;
    float* mem_out = out;                               // [B, H, H]
    float* keys = out + (size_t)BB * H * H;             // [B, S, H]
    float* vals = keys + (size_t)BB * SS * H;           // [B, S, H]
    float* cur = (float*)d_ws;                          // [B, S, 512] = 16 MB

    dim3 gb(8, 128);  // N/64, M/64
    gemm_xwT<<<gb, 256, 0, stream>>>(x, W, cur);
    key_scan<<<64, 64, 0, stream>>>(cur, keys);
    value_scan<<<512, 256, 0, stream>>>(cur, keys, mem_out, vals);
}

// Round 4
// 280.815 us; speedup vs baseline: 2.0530x; 1.3711x over previous
//
#include <hip/hip_runtime.h>

#define BB 16
#define SS 512
#define KIN 512
#define H 256

constexpr float DECAY = 0.951229424500714f;    // exp(-1/20), both tau=20
constexpr float OMD   = 0.048770575499286f;    // 1 - exp(-1/20)
constexpr float LR    = 0.01f;
constexpr float WMAX  = 1.0f;

__device__ __forceinline__ float fast_tanh(float x) {
    float e = __expf(2.f * x);
    return 1.f - __fdividef(2.f, e + 1.f);
}

// All-reduce sum within each 32-lane half.
// 4x DPP row_ror (1,2,4,8) gives every lane its 16-lane-row sum (rotate-allreduce),
// then ds_swizzle xor-16 adds the partner row -> all 32 lanes hold the half-sum.
__device__ __forceinline__ float allsum32(float x) {
    int t;
    t = __builtin_amdgcn_update_dpp(0, __float_as_int(x), 0x121, 0xf, 0xf, false);
    x += __int_as_float(t);
    t = __builtin_amdgcn_update_dpp(0, __float_as_int(x), 0x122, 0xf, 0xf, false);
    x += __int_as_float(t);
    t = __builtin_amdgcn_update_dpp(0, __float_as_int(x), 0x124, 0xf, 0xf, false);
    x += __int_as_float(t);
    t = __builtin_amdgcn_update_dpp(0, __float_as_int(x), 0x128, 0xf, 0xf, false);
    x += __int_as_float(t);
    t = __builtin_amdgcn_ds_swizzle(__float_as_int(x), 0x401F);  // lane ^ 16
    x += __int_as_float(t);
    return x;
}

// OUT[m][n] = sum_k X[m][k] * W[n][k];  X:[8192,512], W:[512,512], OUT:[8192,512]
__global__ __launch_bounds__(256) void gemm_xwT(const float* __restrict__ X,
                                                const float* __restrict__ W,
                                                float* __restrict__ OUT) {
    __shared__ float As[16][68];
    __shared__ float Bs[16][68];
    const int m0 = blockIdx.y * 64;
    const int n0 = blockIdx.x * 64;
    const int tid = threadIdx.x;
    const int r  = tid >> 2;
    const int cg = tid & 3;
    const int tx = tid & 15;
    const int ty = tid >> 4;
    float acc[4][4] = {};
    for (int k0 = 0; k0 < KIN; k0 += 16) {
        float4 av = *(const float4*)&X[(size_t)(m0 + r) * KIN + k0 + cg * 4];
        float4 bv = *(const float4*)&W[(size_t)(n0 + r) * KIN + k0 + cg * 4];
        __syncthreads();
        As[cg*4+0][r] = av.x; As[cg*4+1][r] = av.y; As[cg*4+2][r] = av.z; As[cg*4+3][r] = av.w;
        Bs[cg*4+0][r] = bv.x; Bs[cg*4+1][r] = bv.y; Bs[cg*4+2][r] = bv.z; Bs[cg*4+3][r] = bv.w;
        __syncthreads();
#pragma unroll
        for (int kk = 0; kk < 16; ++kk) {
            float4 a = *(const float4*)&As[kk][ty * 4];
            float4 b = *(const float4*)&Bs[kk][tx * 4];
            float ar[4] = {a.x, a.y, a.z, a.w};
            float br[4] = {b.x, b.y, b.z, b.w};
#pragma unroll
            for (int i = 0; i < 4; ++i)
#pragma unroll
                for (int j = 0; j < 4; ++j) acc[i][j] += ar[i] * br[j];
        }
    }
#pragma unroll
    for (int i = 0; i < 4; ++i) {
        float4 o = make_float4(acc[i][0], acc[i][1], acc[i][2], acc[i][3]);
        *(float4*)&OUT[(size_t)(m0 + ty * 4 + i) * KIN + n0 + tx * 4] = o;
    }
}

// Per (b, col): scan kv/key/kt over time. Writes key to output; overwrites the
// ik slot in cur with kt. 16-deep register prefetch (static indices via unroll).
__global__ __launch_bounds__(64) void key_scan(float* __restrict__ cur,
                                               float* __restrict__ keys) {
    const int idx = blockIdx.x * 64 + threadIdx.x;   // 0..4095
    const int b   = idx >> 8;
    const int col = idx & 255;
    float* c  = cur  + (size_t)b * SS * 512 + col;
    float* ko = keys + (size_t)b * SS * H + col;
    float kv = 0.f, kt = 0.f;

    constexpr int D = 16;
    float ib[D];
#pragma unroll
    for (int j = 0; j < D; ++j) ib[j] = c[(size_t)j * 512];

    for (int t = 0; t < SS; t += D) {
#pragma unroll
        for (int j = 0; j < D; ++j) {
            float ik = ib[j];
            int tn = t + D + j; if (tn > SS - 1) tn = SS - 1;
            ib[j] = c[(size_t)tn * 512];   // prefetch D steps ahead (dead on tail)
            kv = DECAY * kv + ik;
            float key = fast_tanh(kv);
            kt = DECAY * kt + OMD * key;
            ko[(size_t)(t + j) * H] = key;
            c[(size_t)(t + j) * 512] = kt;
        }
    }
}

// cur: [B,S,512] cols 0-255 = kt (from key_scan), 256-511 = iv.
// 2 mem-rows per wave (32 lanes/row, 8 cols/lane), 8-deep register prefetch.
// Block swizzle: b = bid & 15 so all 32 blocks of a batch share an XCD (16%8==0).
__global__ __launch_bounds__(256) void value_scan(const float* __restrict__ cur,
                                                  const float* __restrict__ keys,
                                                  float* __restrict__ mem_out,
                                                  float* __restrict__ vals) {
    const int tid  = threadIdx.x;
    const int wave = tid >> 6;
    const int lane = tid & 63;
    const int half = lane >> 5;
    const int sub  = lane & 31;
    const int b    = blockIdx.x & 15;
    const int rg   = blockIdx.x >> 4;
    const int row  = rg * 8 + wave * 2 + half;

    const float* ktp  = cur  + (size_t)b * SS * 512 + sub * 8;
    const float* ivp  = cur  + (size_t)b * SS * 512 + 256 + row;
    const float* keyp = keys + (size_t)b * SS * H + sub * 8;
    float* valout = vals + (size_t)b * SS * H;

    float mem[8] = {0.f, 0.f, 0.f, 0.f, 0.f, 0.f, 0.f, 0.f};
    float vv = 0.f, vt = 0.f;

    constexpr int D = 8;
    float4 kb0[D], kb1[D], tb0[D], tb1[D];
    float  ib[D];
#pragma unroll
    for (int j = 0; j < D; ++j) {
        kb0[j] = *(const float4*)&keyp[(size_t)j * H];
        kb1[j] = *(const float4*)&keyp[(size_t)j * H + 4];
        tb0[j] = *(const float4*)&ktp[(size_t)j * 512];
        tb1[j] = *(const float4*)&ktp[(size_t)j * 512 + 4];
        ib[j]  = ivp[(size_t)j * 512];
    }

    for (int t = 0; t < SS; t += D) {
#pragma unroll
        for (int j = 0; j < D; ++j) {
            float4 ck0 = kb0[j], ck1 = kb1[j];
            float4 ct0 = tb0[j], ct1 = tb1[j];
            float  civ = ib[j];

            int tn = t + D + j; if (tn > SS - 1) tn = SS - 1;
            kb0[j] = *(const float4*)&keyp[(size_t)tn * H];
            kb1[j] = *(const float4*)&keyp[(size_t)tn * H + 4];
            tb0[j] = *(const float4*)&ktp[(size_t)tn * 512];
            tb1[j] = *(const float4*)&ktp[(size_t)tn * 512 + 4];
            ib[j]  = ivp[(size_t)tn * 512];

            // readout: this row dotted with key, all-reduced over the 32-lane half
            float p = mem[0] * ck0.x + mem[1] * ck0.y + mem[2] * ck0.z + mem[3] * ck0.w
                    + mem[4] * ck1.x + mem[5] * ck1.y + mem[6] * ck1.z + mem[7] * ck1.w;
            float ikv = 0.2f * allsum32(p);

            // value dynamics (uniform across the 32 lanes of this row)
            vv = DECAY * vv + civ + ikv;
            float valv = fast_tanh(vv);
            vt = DECAY * vt + OMD * valv;
            if (sub == 0) valout[(size_t)(t + j) * H + row] = valv;

            // soft-bounded Hebbian update, kt precomputed
            float c = LR * vt;
            mem[0] += (c * ct0.x) * (WMAX - mem[0]);
            mem[1] += (c * ct0.y) * (WMAX - mem[1]);
            mem[2] += (c * ct0.z) * (WMAX - mem[2]);
            mem[3] += (c * ct0.w) * (WMAX - mem[3]);
            mem[4] += (c * ct1.x) * (WMAX - mem[4]);
            mem[5] += (c * ct1.y) * (WMAX - mem[5]);
            mem[6] += (c * ct1.z) * (WMAX - mem[6]);
            mem[7] += (c * ct1.w) * (WMAX - mem[7]);
        }
    }

    float* mo = &mem_out[((size_t)b * H + row) * H + sub * 8];
    *(float4*)&mo[0] = make_float4(mem[0], mem[1], mem[2], mem[3]);
    *(float4*)&mo[4] = make_float4(mem[4], mem[5], mem[6], mem[7]);
}

extern "C" void kernel_launch(void* const* d_in, const int* in_sizes, int n_in,
                              void* d_out, int out_size, void* d_ws, size_t ws_size,
                              hipStream_t stream) {
    const float* x = (const float*)d_in[0];   // [B, S, IN] f32
    const float* W = (const float*)d_in[1];   // [2H, IN] f32
    float* out = (float*)d_out;
    float* mem_out = out;                               // [B, H, H]
    float* keys = out + (size_t)BB * H * H;             // [B, S, H]
    float* vals = keys + (size_t)BB * SS * H;           // [B, S, H]
    float* cur = (float*)d_ws;                          // [B, S, 512] = 16 MB

    dim3 gb(8, 128);  // N/64, M/64
    gemm_xwT<<<gb, 256, 0, stream>>>(x, W, cur);
    key_scan<<<64, 64, 0, stream>>>(cur, keys);
    value_scan<<<512, 256, 0, stream>>>(cur, keys, mem_out, vals);
}

// Round 5
// 259.481 us; speedup vs baseline: 2.2218x; 1.0822x over previous
//
#include <hip/hip_runtime.h>

#define BB 16
#define SS 512
#define KIN 512
#define H 256

typedef float v2f __attribute__((ext_vector_type(2)));

constexpr float DECAY = 0.951229424500714f;    // exp(-1/20), both tau=20
constexpr float OMD   = 0.048770575499286f;    // 1 - exp(-1/20)
constexpr float LR    = 0.01f;
constexpr float WMAX  = 1.0f;

__device__ __forceinline__ float fast_tanh(float x) {
    float e = __expf(2.f * x);
    return 1.f - __fdividef(2.f, e + 1.f);
}

// All-reduce sum within each 32-lane half (verified rounds 3-4).
__device__ __forceinline__ float allsum32(float x) {
    int t;
    t = __builtin_amdgcn_update_dpp(0, __float_as_int(x), 0x121, 0xf, 0xf, false);
    x += __int_as_float(t);
    t = __builtin_amdgcn_update_dpp(0, __float_as_int(x), 0x122, 0xf, 0xf, false);
    x += __int_as_float(t);
    t = __builtin_amdgcn_update_dpp(0, __float_as_int(x), 0x124, 0xf, 0xf, false);
    x += __int_as_float(t);
    t = __builtin_amdgcn_update_dpp(0, __float_as_int(x), 0x128, 0xf, 0xf, false);
    x += __int_as_float(t);
    t = __builtin_amdgcn_ds_swizzle(__float_as_int(x), 0x401F);  // lane ^ 16
    x += __int_as_float(t);
    return x;
}

// i = x @ W^T. ik half (n<256) -> ik_out[b*512+s][256]; iv half -> iv_t[b][row][s].
__global__ __launch_bounds__(256) void gemm_xwT(const float* __restrict__ X,
                                                const float* __restrict__ W,
                                                float* __restrict__ ik_out,
                                                float* __restrict__ iv_t) {
    __shared__ float As[16][68];
    __shared__ float Bs[16][68];
    const int m0 = blockIdx.y * 64;
    const int n0 = blockIdx.x * 64;
    const int tid = threadIdx.x;
    const int r  = tid >> 2;
    const int cg = tid & 3;
    const int tx = tid & 15;
    const int ty = tid >> 4;
    float acc[4][4] = {};
    for (int k0 = 0; k0 < KIN; k0 += 16) {
        float4 av = *(const float4*)&X[(size_t)(m0 + r) * KIN + k0 + cg * 4];
        float4 bv = *(const float4*)&W[(size_t)(n0 + r) * KIN + k0 + cg * 4];
        __syncthreads();
        As[cg*4+0][r] = av.x; As[cg*4+1][r] = av.y; As[cg*4+2][r] = av.z; As[cg*4+3][r] = av.w;
        Bs[cg*4+0][r] = bv.x; Bs[cg*4+1][r] = bv.y; Bs[cg*4+2][r] = bv.z; Bs[cg*4+3][r] = bv.w;
        __syncthreads();
#pragma unroll
        for (int kk = 0; kk < 16; ++kk) {
            float4 a = *(const float4*)&As[kk][ty * 4];
            float4 b = *(const float4*)&Bs[kk][tx * 4];
            float ar[4] = {a.x, a.y, a.z, a.w};
            float br[4] = {b.x, b.y, b.z, b.w};
#pragma unroll
            for (int i = 0; i < 4; ++i)
#pragma unroll
                for (int j = 0; j < 4; ++j) acc[i][j] += ar[i] * br[j];
        }
    }
    if (n0 < 256) {
#pragma unroll
        for (int i = 0; i < 4; ++i) {
            float4 o = make_float4(acc[i][0], acc[i][1], acc[i][2], acc[i][3]);
            *(float4*)&ik_out[(size_t)(m0 + ty * 4 + i) * 256 + n0 + tx * 4] = o;
        }
    } else {
        const int b  = m0 >> 9;
        const int s0 = (m0 & 511) + ty * 4;
#pragma unroll
        for (int j = 0; j < 4; ++j) {
            float4 o = make_float4(acc[0][j], acc[1][j], acc[2][j], acc[3][j]);
            *(float4*)&iv_t[((size_t)b * H + (n0 - 256 + tx * 4 + j)) * SS + s0] = o;
        }
    }
}

// Per (b, col): scan kv, write key only. 32-deep prefetch, compact ik layout.
__global__ __launch_bounds__(64) void key_scan(const float* __restrict__ ik,
                                               float* __restrict__ keys) {
    const int idx = blockIdx.x * 64 + threadIdx.x;   // 0..4095
    const int b   = idx >> 8;
    const int col = idx & 255;
    const float* c  = ik + (size_t)b * SS * 256 + col;
    float* ko = keys + (size_t)b * SS * H + col;
    float kv = 0.f;
    constexpr int D = 32;
    float ib[D];
#pragma unroll
    for (int j = 0; j < D; ++j) ib[j] = c[(size_t)j * 256];
    for (int t = 0; t < SS; t += D) {
#pragma unroll
        for (int j = 0; j < D; ++j) {
            float v = ib[j];
            int tn = t + D + j; if (tn > SS - 1) tn = SS - 1;
            ib[j] = c[(size_t)tn * 256];
            kv = DECAY * kv + v;
            ko[(size_t)(t + j) * H] = fast_tanh(kv);
        }
    }
}

// 2 mem-rows per wave (32 lanes/row, 8 cols/lane). kt computed in registers.
// keys read via uniform base + imm lane offset; iv via transposed contiguous tiles.
__global__ __launch_bounds__(256) void value_scan(const float* __restrict__ keys,
                                                  const float* __restrict__ iv_t,
                                                  float* __restrict__ mem_out,
                                                  float* __restrict__ vals) {
    const int tid  = threadIdx.x;
    const int wave = tid >> 6;
    const int lane = tid & 63;
    const int half = lane >> 5;
    const int sub  = lane & 31;
    const int b    = blockIdx.x & 15;     // XCD swizzle: batch-mates share an XCD
    const int rg   = blockIdx.x >> 4;
    const int row  = rg * 8 + wave * 2 + half;
    const int so   = sub * 8;

    const float* kb  = keys + (size_t)b * SS * H;           // uniform base
    const float* ivb = iv_t + ((size_t)b * H + row) * SS;   // per-row base
    float* valout = vals + (size_t)b * SS * H;

    const v2f DEC2 = {DECAY, DECAY};
    const v2f OMD2 = {OMD, OMD};
    const v2f W2   = {WMAX, WMAX};

    v2f mem2[4] = {{0.f,0.f},{0.f,0.f},{0.f,0.f},{0.f,0.f}};
    v2f ktr2[4] = {{0.f,0.f},{0.f,0.f},{0.f,0.f},{0.f,0.f}};
    float vv = 0.f, vt = 0.f;

    // key ring: 8 steps deep
    float4 kA[8], kB[8];
#pragma unroll
    for (int j = 0; j < 8; ++j) {
        kA[j] = *(const float4*)&kb[(size_t)j * H + so];
        kB[j] = *(const float4*)&kb[(size_t)j * H + so + 4];
    }
    // iv tiles (8 steps each), double-buffered
    float4 ivA0 = *(const float4*)&ivb[0];
    float4 ivA1 = *(const float4*)&ivb[4];
    float4 ivB0 = *(const float4*)&ivb[8];
    float4 ivB1 = *(const float4*)&ivb[12];

    auto step = [&](int t, int j, float civ) {
        float4 kc0 = kA[j], kc1 = kB[j];
        int tn = t + 8 + j; if (tn > SS - 1) tn = SS - 1;
        kA[j] = *(const float4*)&kb[(size_t)tn * H + so];
        kB[j] = *(const float4*)&kb[(size_t)tn * H + so + 4];
        v2f kc2[4] = {{kc0.x, kc0.y}, {kc0.z, kc0.w}, {kc1.x, kc1.y}, {kc1.z, kc1.w}};
        v2f p2 = mem2[0] * kc2[0] + mem2[1] * kc2[1]
               + mem2[2] * kc2[2] + mem2[3] * kc2[3];
        float ikv = 0.2f * allsum32(p2.x + p2.y);
        vv = DECAY * vv + civ + ikv;
        float valv = fast_tanh(vv);
        vt = DECAY * vt + OMD * valv;
        if (sub == 0) valout[(size_t)(t + j) * H + row] = valv;
        v2f c2 = {LR * vt, LR * vt};
#pragma unroll
        for (int q = 0; q < 4; ++q) {
            ktr2[q] = DEC2 * ktr2[q] + OMD2 * kc2[q];
            mem2[q] += (c2 * ktr2[q]) * (W2 - mem2[q]);
        }
    };

    for (int t0 = 0; t0 < SS; t0 += 16) {
        {   // even tile: consume ivA, prefetch tile t0/8 + 2
            float iva[8] = {ivA0.x, ivA0.y, ivA0.z, ivA0.w, ivA1.x, ivA1.y, ivA1.z, ivA1.w};
            int tp = t0 + 16; if (tp > SS - 8) tp = SS - 8;
            ivA0 = *(const float4*)&ivb[tp];
            ivA1 = *(const float4*)&ivb[tp + 4];
#pragma unroll
            for (int j = 0; j < 8; ++j) step(t0, j, iva[j]);
        }
        {   // odd tile: consume ivB, prefetch tile t0/8 + 3
            float ivc[8] = {ivB0.x, ivB0.y, ivB0.z, ivB0.w, ivB1.x, ivB1.y, ivB1.z, ivB1.w};
            int tp = t0 + 24; if (tp > SS - 8) tp = SS - 8;
            ivB0 = *(const float4*)&ivb[tp];
            ivB1 = *(const float4*)&ivb[tp + 4];
#pragma unroll
            for (int j = 0; j < 8; ++j) step(t0 + 8, j, ivc[j]);
        }
    }

    float* mo = &mem_out[((size_t)b * H + row) * H + so];
    *(float4*)&mo[0] = make_float4(mem2[0].x, mem2[0].y, mem2[1].x, mem2[1].y);
    *(float4*)&mo[4] = make_float4(mem2[2].x, mem2[2].y, mem2[3].x, mem2[3].y);
}

extern "C" void kernel_launch(void* const* d_in, const int* in_sizes, int n_in,
                              void* d_out, int out_size, void* d_ws, size_t ws_size,
                              hipStream_t stream) {
    const float* x = (const float*)d_in[0];   // [B, S, IN] f32
    const float* W = (const float*)d_in[1];   // [2H, IN] f32
    float* out = (float*)d_out;
    float* mem_out = out;                               // [B, H, H]
    float* keys = out + (size_t)BB * H * H;             // [B, S, H]
    float* vals = keys + (size_t)BB * SS * H;           // [B, S, H]
    float* ik   = (float*)d_ws;                         // [B*S, 256]  8 MB
    float* iv_t = ik + (size_t)BB * SS * 256;           // [B, H, S]   8 MB

    dim3 gb(8, 128);  // N/64, M/64
    gemm_xwT<<<gb, 256, 0, stream>>>(x, W, ik, iv_t);
    key_scan<<<64, 64, 0, stream>>>(ik, keys);
    value_scan<<<512, 256, 0, stream>>>(keys, iv_t, mem_out, vals);
}